// Round 1
// baseline (295.343 us; speedup 1.0000x reference)
//
#include <hip/hip_runtime.h>
#include <hip/hip_bf16.h>

#define BM 128
#define BN 128
#define BK 32
#define TB 256

typedef __attribute__((ext_vector_type(8))) short bf16x8;
typedef __attribute__((ext_vector_type(4))) float f32x4;
typedef __attribute__((ext_vector_type(4))) int   i32x4;

static __device__ inline int pk2(float a, float b) {
    // two fp32 -> packed bf16 (RNE); compiler should emit v_cvt_pk_bf16_f32
    __hip_bfloat162 h = __float22bfloat162_rn(float2{a, b});
    int r;
    __builtin_memcpy(&r, &h, 4);
    return r;
}

__global__ __launch_bounds__(TB) void bgemm_bt_bias(
    const float* __restrict__ X,     // [8, 8192, 512]
    const float* __restrict__ Wt,    // [8, 512, 512]  (row o, k-contiguous)
    const float* __restrict__ Bias,  // [8, 512]
    float* __restrict__ Out)         // [8, 8192, 512]
{
    const int b   = blockIdx.z;
    const int m0  = blockIdx.y * BM;
    const int n0  = blockIdx.x * BN;
    const int tid = threadIdx.x;
    const int lane = tid & 63;
    const int wave = tid >> 6;
    const int wm = (wave >> 1) * 64;   // wave's row offset within tile
    const int wn = (wave & 1) * 64;    // wave's col offset within tile

    __shared__ short As[BM * BK];      // bf16 bits, row-major [row][k], stride 32
    __shared__ short Bs[BN * BK];

    // ---- staging assignment: thread -> (row, k-half) ----
    const int srow  = tid >> 1;        // 0..127
    const int khalf = (tid & 1) * 16;  // 0 or 16 (floats)

    const float* xg = X  + ((size_t)b * 8192 + m0 + srow) * 512 + khalf;
    const float* wg = Wt + ((size_t)b * 512  + n0 + srow) * 512 + khalf;

    f32x4 ax[4], bx[4];
    {
        const f32x4* xa = (const f32x4*)xg;
        const f32x4* wa = (const f32x4*)wg;
#pragma unroll
        for (int i = 0; i < 4; ++i) { ax[i] = xa[i]; bx[i] = wa[i]; }
    }

    f32x4 acc[4][4];
#pragma unroll
    for (int i = 0; i < 4; ++i)
#pragma unroll
        for (int j = 0; j < 4; ++j)
            acc[i][j] = (f32x4){0.f, 0.f, 0.f, 0.f};

    const int frow = lane & 15;        // fragment row (m or n within 16)
    const int fk   = (lane >> 4) * 8;  // fragment k offset

    const int KSTEPS = 512 / BK;       // 16
    for (int ks = 0; ks < KSTEPS; ++ks) {
        __syncthreads();  // previous iteration's ds_reads complete

        // convert staged fp32 -> bf16, write to LDS (2x ds_write_b128 per tile)
#pragma unroll
        for (int i = 0; i < 2; ++i) {
            i32x4 pw;
            pw[0] = pk2(ax[2*i][0],   ax[2*i][1]);
            pw[1] = pk2(ax[2*i][2],   ax[2*i][3]);
            pw[2] = pk2(ax[2*i+1][0], ax[2*i+1][1]);
            pw[3] = pk2(ax[2*i+1][2], ax[2*i+1][3]);
            *(i32x4*)&As[srow * BK + khalf + 8 * i] = pw;
        }
#pragma unroll
        for (int i = 0; i < 2; ++i) {
            i32x4 pw;
            pw[0] = pk2(bx[2*i][0],   bx[2*i][1]);
            pw[1] = pk2(bx[2*i][2],   bx[2*i][3]);
            pw[2] = pk2(bx[2*i+1][0], bx[2*i+1][1]);
            pw[3] = pk2(bx[2*i+1][2], bx[2*i+1][3]);
            *(i32x4*)&Bs[srow * BK + khalf + 8 * i] = pw;
        }

        __syncthreads();  // writes visible

        // prefetch next K-tile while MFMA section runs
        if (ks + 1 < KSTEPS) {
            const f32x4* xa = (const f32x4*)(xg + (ks + 1) * BK);
            const f32x4* wa = (const f32x4*)(wg + (ks + 1) * BK);
#pragma unroll
            for (int i = 0; i < 4; ++i) { ax[i] = xa[i]; bx[i] = wa[i]; }
        }

        bf16x8 af[4], bfr[4];
#pragma unroll
        for (int mf = 0; mf < 4; ++mf)
            af[mf] = *(const bf16x8*)&As[(wm + mf * 16 + frow) * BK + fk];
#pragma unroll
        for (int nf = 0; nf < 4; ++nf)
            bfr[nf] = *(const bf16x8*)&Bs[(wn + nf * 16 + frow) * BK + fk];

#pragma unroll
        for (int mf = 0; mf < 4; ++mf)
#pragma unroll
            for (int nf = 0; nf < 4; ++nf)
                acc[mf][nf] = __builtin_amdgcn_mfma_f32_16x16x32_bf16(
                    af[mf], bfr[nf], acc[mf][nf], 0, 0, 0);
    }

    // ---- epilogue: add bias, store fp32 ----
    float bv[4];
    const float* biasp = Bias + (size_t)b * 512 + n0 + wn;
#pragma unroll
    for (int nf = 0; nf < 4; ++nf)
        bv[nf] = biasp[nf * 16 + frow];

    float* outp = Out + ((size_t)b * 8192 + m0 + wm) * 512 + n0 + wn;
    const int orow = (lane >> 4) * 4;  // C/D: row = (lane>>4)*4 + reg
#pragma unroll
    for (int mf = 0; mf < 4; ++mf)
#pragma unroll
        for (int nf = 0; nf < 4; ++nf)
#pragma unroll
            for (int r = 0; r < 4; ++r)
                outp[(size_t)(mf * 16 + orow + r) * 512 + nf * 16 + frow] =
                    acc[mf][nf][r] + bv[nf];
}

extern "C" void kernel_launch(void* const* d_in, const int* in_sizes, int n_in,
                              void* d_out, int out_size, void* d_ws, size_t ws_size,
                              hipStream_t stream) {
    const float* X    = (const float*)d_in[0];
    const float* Wt   = (const float*)d_in[1];
    const float* Bias = (const float*)d_in[2];
    float* Out        = (float*)d_out;

    dim3 grid(512 / BN, 8192 / BM, 8);  // n-tiles fastest for x-panel LLC reuse
    bgemm_bt_bias<<<grid, TB, 0, stream>>>(X, Wt, Bias, Out);
}

// Round 2
// 290.672 us; speedup vs baseline: 1.0161x; 1.0161x over previous
//
#include <hip/hip_runtime.h>
#include <hip/hip_bf16.h>

#define BM 128
#define BN 128
#define BK 32
#define TB 256
#define LDK 40   // padded LDS row stride in bf16 elems (80 B) -> conflict-free b128 r/w

typedef __attribute__((ext_vector_type(8))) short bf16x8;
typedef __attribute__((ext_vector_type(4))) float f32x4;
typedef __attribute__((ext_vector_type(4))) int   i32x4;

static __device__ inline int pk2(float a, float b) {
    // two fp32 -> packed bf16 (RNE)
    __hip_bfloat162 h = __float22bfloat162_rn(float2{a, b});
    int r;
    __builtin_memcpy(&r, &h, 4);
    return r;
}

__global__ __launch_bounds__(TB, 4) void bgemm_bt_bias(
    const float* __restrict__ X,     // [8, 8192, 512]
    const float* __restrict__ Wt,    // [8, 512, 512]
    const float* __restrict__ Bias,  // [8, 512]
    float* __restrict__ Out)         // [8, 8192, 512]
{
    // ---- XCD-aware swizzle: the 4 n-tiles sharing an x-panel land on one XCD ----
    const int flat  = blockIdx.x;          // 0..2047
    const int xcd   = flat & 7;
    const int rr    = flat >> 3;           // 0..255
    const int nt    = rr & 3;              // n-tile (innermost within an XCD)
    const int p     = rr >> 2;             // 0..63
    const int panel = p * 8 + xcd;         // 0..511  (b, m) panel
    const int mt    = panel & 63;
    const int b     = panel >> 6;

    const int m0  = mt * BM;
    const int n0  = nt * BN;
    const int tid = threadIdx.x;
    const int lane = tid & 63;
    const int wave = tid >> 6;
    const int wm = (wave >> 1) * 64;
    const int wn = (wave & 1) * 64;

    __shared__ short As[2][BM * LDK];   // double-buffered, padded stride
    __shared__ short Bs[2][BN * LDK];

    // staging assignment: thread -> (row, k-half)
    const int srow  = tid >> 1;          // 0..127
    const int khalf = (tid & 1) * 16;    // float offset 0 or 16

    const float* xg = X  + ((size_t)b * 8192 + m0 + srow) * 512 + khalf;
    const float* wg = Wt + ((size_t)b * 512  + n0 + srow) * 512 + khalf;

    const int swoff = srow * LDK + khalf;  // LDS write offset (shorts)

    f32x4 ax[4], bx[4];

    // ---- prologue: tile 0 -> buf 0 ----
    {
        const f32x4* xa = (const f32x4*)xg;
        const f32x4* wa = (const f32x4*)wg;
#pragma unroll
        for (int i = 0; i < 4; ++i) { ax[i] = xa[i]; bx[i] = wa[i]; }
#pragma unroll
        for (int i = 0; i < 2; ++i) {
            i32x4 pw;
            pw[0] = pk2(ax[2*i][0],   ax[2*i][1]);
            pw[1] = pk2(ax[2*i][2],   ax[2*i][3]);
            pw[2] = pk2(ax[2*i+1][0], ax[2*i+1][1]);
            pw[3] = pk2(ax[2*i+1][2], ax[2*i+1][3]);
            *(i32x4*)&As[0][swoff + 8 * i] = pw;
        }
#pragma unroll
        for (int i = 0; i < 2; ++i) {
            i32x4 pw;
            pw[0] = pk2(bx[2*i][0],   bx[2*i][1]);
            pw[1] = pk2(bx[2*i][2],   bx[2*i][3]);
            pw[2] = pk2(bx[2*i+1][0], bx[2*i+1][1]);
            pw[3] = pk2(bx[2*i+1][2], bx[2*i+1][3]);
            *(i32x4*)&Bs[0][swoff + 8 * i] = pw;
        }
    }
    __syncthreads();

    f32x4 acc[4][4];
#pragma unroll
    for (int i = 0; i < 4; ++i)
#pragma unroll
        for (int j = 0; j < 4; ++j)
            acc[i][j] = (f32x4){0.f, 0.f, 0.f, 0.f};

    const int frow = lane & 15;
    const int fk   = (lane >> 4) * 8;

    const int KSTEPS = 512 / BK;   // 16
#pragma unroll 2
    for (int ks = 0; ks < KSTEPS; ++ks) {
        const int cur = ks & 1;
        const int nxt = cur ^ 1;

        // issue next tile's global loads immediately after the barrier:
        // consumed at the bottom of this iteration -> ds_read+MFMA cover the latency,
        // and vmcnt is already 0 when we hit the next barrier (no naked drain).
        if (ks + 1 < KSTEPS) {
            const f32x4* xa = (const f32x4*)(xg + (ks + 1) * BK);
            const f32x4* wa = (const f32x4*)(wg + (ks + 1) * BK);
#pragma unroll
            for (int i = 0; i < 4; ++i) { ax[i] = xa[i]; bx[i] = wa[i]; }
        }

        // fragments from current buffer
        bf16x8 af[4], bfr[4];
#pragma unroll
        for (int mf = 0; mf < 4; ++mf)
            af[mf] = *(const bf16x8*)&As[cur][(wm + mf * 16 + frow) * LDK + fk];
#pragma unroll
        for (int nf = 0; nf < 4; ++nf)
            bfr[nf] = *(const bf16x8*)&Bs[cur][(wn + nf * 16 + frow) * LDK + fk];

#pragma unroll
        for (int mf = 0; mf < 4; ++mf)
#pragma unroll
            for (int nf = 0; nf < 4; ++nf)
                acc[mf][nf] = __builtin_amdgcn_mfma_f32_16x16x32_bf16(
                    af[mf], bfr[nf], acc[mf][nf], 0, 0, 0);

        // convert + write next tile into the other buffer (safe: other waves'
        // reads of buf[nxt] finished before the *previous* barrier)
        if (ks + 1 < KSTEPS) {
#pragma unroll
            for (int i = 0; i < 2; ++i) {
                i32x4 pw;
                pw[0] = pk2(ax[2*i][0],   ax[2*i][1]);
                pw[1] = pk2(ax[2*i][2],   ax[2*i][3]);
                pw[2] = pk2(ax[2*i+1][0], ax[2*i+1][1]);
                pw[3] = pk2(ax[2*i+1][2], ax[2*i+1][3]);
                *(i32x4*)&As[nxt][swoff + 8 * i] = pw;
            }
#pragma unroll
            for (int i = 0; i < 2; ++i) {
                i32x4 pw;
                pw[0] = pk2(bx[2*i][0],   bx[2*i][1]);
                pw[1] = pk2(bx[2*i][2],   bx[2*i][3]);
                pw[2] = pk2(bx[2*i+1][0], bx[2*i+1][1]);
                pw[3] = pk2(bx[2*i+1][2], bx[2*i+1][3]);
                *(i32x4*)&Bs[nxt][swoff + 8 * i] = pw;
            }
        }

        __syncthreads();
    }

    // ---- epilogue: add bias, store fp32 ----
    float bv[4];
    const float* biasp = Bias + (size_t)b * 512 + n0 + wn;
#pragma unroll
    for (int nf = 0; nf < 4; ++nf)
        bv[nf] = biasp[nf * 16 + frow];

    float* outp = Out + ((size_t)b * 8192 + m0 + wm) * 512 + n0 + wn;
    const int orow = (lane >> 4) * 4;   // C/D: row = (lane>>4)*4 + reg
#pragma unroll
    for (int mf = 0; mf < 4; ++mf)
#pragma unroll
        for (int nf = 0; nf < 4; ++nf)
#pragma unroll
            for (int r = 0; r < 4; ++r)
                outp[(size_t)(mf * 16 + orow + r) * 512 + nf * 16 + frow] =
                    acc[mf][nf][r] + bv[nf];
}

extern "C" void kernel_launch(void* const* d_in, const int* in_sizes, int n_in,
                              void* d_out, int out_size, void* d_ws, size_t ws_size,
                              hipStream_t stream) {
    const float* X    = (const float*)d_in[0];
    const float* Wt   = (const float*)d_in[1];
    const float* Bias = (const float*)d_in[2];
    float* Out        = (float*)d_out;

    dim3 grid(2048);  // 1D; XCD swizzle decoded in-kernel
    bgemm_bt_bias<<<grid, TB, 0, stream>>>(X, Wt, Bias, Out);
}

// Round 3
// 278.194 us; speedup vs baseline: 1.0616x; 1.0449x over previous
//
#include <hip/hip_runtime.h>
#include <hip/hip_bf16.h>

#define BM 128
#define BN 128
#define BK 32
#define TB 256
#define LDK 40   // padded LDS row stride (80 B): b128 frag reads conflict-free,
                 // b64 slab writes <=2-way (free per m136)

typedef __attribute__((ext_vector_type(8))) short bf16x8;
typedef __attribute__((ext_vector_type(4))) float f32x4;
typedef __attribute__((ext_vector_type(2))) int   i32x2;

static __device__ inline int pk2(float a, float b) {
    // two fp32 -> packed bf16 (RNE)
    __hip_bfloat162 h = __float22bfloat162_rn(float2{a, b});
    int r;
    __builtin_memcpy(&r, &h, 4);
    return r;
}

__global__ __launch_bounds__(TB) void bgemm_bt_bias(
    const float* __restrict__ X,     // [8, 8192, 512]
    const float* __restrict__ Wt,    // [8, 512, 512]
    const float* __restrict__ Bias,  // [8, 512]
    float* __restrict__ Out)         // [8, 8192, 512]
{
    // XCD-aware swizzle: 4 n-tiles sharing an x-panel land on one XCD (R2 win: FETCH 270->103MB)
    const int flat  = blockIdx.x;          // 0..2047
    const int xcd   = flat & 7;
    const int rr    = flat >> 3;
    const int nt    = rr & 3;
    const int p     = rr >> 2;
    const int panel = p * 8 + xcd;
    const int mt    = panel & 63;
    const int b     = panel >> 6;

    const int m0  = mt * BM;
    const int n0  = nt * BN;
    const int tid = threadIdx.x;
    const int lane = tid & 63;
    const int wave = tid >> 6;
    const int wm = (wave >> 1) * 64;
    const int wn = (wave & 1) * 64;

    __shared__ short As[2][BM * LDK];
    __shared__ short Bs[2][BN * LDK];

    // ---- slab-coalesced staging: thread t, chunk i -> row i*32+(t>>3), 16B at col (t&7)*4 floats.
    // Per load instr: 8 rows x 128 B contiguous = fully coalesced (16 lines/KB, was 64).
    const int lrow = tid >> 3;         // 0..31
    const int lcol = (tid & 7) * 4;    // float col within the 32-float K chunk

    const float* xg = X  + ((size_t)b * 8192 + m0 + lrow) * 512 + lcol;
    const float* wg = Wt + ((size_t)b * 512  + n0 + lrow) * 512 + lcol;
    // chunk i adds i*32 rows = i*32*512 floats; K-step ks adds ks*32 floats

    f32x4 ax[4], bx[4];

    // ---- prologue: tile 0 -> buf 0 ----
    {
#pragma unroll
        for (int i = 0; i < 4; ++i) {
            ax[i] = *(const f32x4*)(xg + (size_t)i * 32 * 512);
            bx[i] = *(const f32x4*)(wg + (size_t)i * 32 * 512);
        }
#pragma unroll
        for (int i = 0; i < 4; ++i) {
            i32x2 pa; pa[0] = pk2(ax[i][0], ax[i][1]); pa[1] = pk2(ax[i][2], ax[i][3]);
            *(i32x2*)&As[0][(i * 32 + lrow) * LDK + lcol] = pa;
            i32x2 pb; pb[0] = pk2(bx[i][0], bx[i][1]); pb[1] = pk2(bx[i][2], bx[i][3]);
            *(i32x2*)&Bs[0][(i * 32 + lrow) * LDK + lcol] = pb;
        }
    }
    __syncthreads();

    f32x4 acc[4][4];
#pragma unroll
    for (int i = 0; i < 4; ++i)
#pragma unroll
        for (int j = 0; j < 4; ++j)
            acc[i][j] = (f32x4){0.f, 0.f, 0.f, 0.f};

    const int frow = lane & 15;
    const int fk   = (lane >> 4) * 8;

    const int KSTEPS = 512 / BK;   // 16
#pragma unroll 2
    for (int ks = 0; ks < KSTEPS; ++ks) {
        const int cur = ks & 1;
        const int nxt = cur ^ 1;

        // issue next tile's (coalesced) loads right after the barrier; consumed
        // after the MFMA section so ds_read+MFMA cover the L2 latency
        if (ks + 1 < KSTEPS) {
#pragma unroll
            for (int i = 0; i < 4; ++i) {
                ax[i] = *(const f32x4*)(xg + (size_t)i * 32 * 512 + (ks + 1) * BK);
                bx[i] = *(const f32x4*)(wg + (size_t)i * 32 * 512 + (ks + 1) * BK);
            }
        }

        bf16x8 af[4], bfr[4];
#pragma unroll
        for (int mf = 0; mf < 4; ++mf)
            af[mf] = *(const bf16x8*)&As[cur][(wm + mf * 16 + frow) * LDK + fk];
#pragma unroll
        for (int nf = 0; nf < 4; ++nf)
            bfr[nf] = *(const bf16x8*)&Bs[cur][(wn + nf * 16 + frow) * LDK + fk];

#pragma unroll
        for (int mf = 0; mf < 4; ++mf)
#pragma unroll
            for (int nf = 0; nf < 4; ++nf)
                acc[mf][nf] = __builtin_amdgcn_mfma_f32_16x16x32_bf16(
                    af[mf], bfr[nf], acc[mf][nf], 0, 0, 0);

        if (ks + 1 < KSTEPS) {
#pragma unroll
            for (int i = 0; i < 4; ++i) {
                i32x2 pa; pa[0] = pk2(ax[i][0], ax[i][1]); pa[1] = pk2(ax[i][2], ax[i][3]);
                *(i32x2*)&As[nxt][(i * 32 + lrow) * LDK + lcol] = pa;
                i32x2 pb; pb[0] = pk2(bx[i][0], bx[i][1]); pb[1] = pk2(bx[i][2], bx[i][3]);
                *(i32x2*)&Bs[nxt][(i * 32 + lrow) * LDK + lcol] = pb;
            }
        }

        __syncthreads();
    }

    // ---- epilogue: add bias, store fp32 ----
    // each quarter-wave (16 lanes, frow 0..15) writes one full aligned 64-B line:
    // line-request count already minimal; no LDS staging needed
    float bv[4];
    const float* biasp = Bias + (size_t)b * 512 + n0 + wn;
#pragma unroll
    for (int nf = 0; nf < 4; ++nf)
        bv[nf] = biasp[nf * 16 + frow];

    float* outp = Out + ((size_t)b * 8192 + m0 + wm) * 512 + n0 + wn;
    const int orow = (lane >> 4) * 4;   // C/D: row = (lane>>4)*4 + reg
#pragma unroll
    for (int mf = 0; mf < 4; ++mf)
#pragma unroll
        for (int nf = 0; nf < 4; ++nf)
#pragma unroll
            for (int r = 0; r < 4; ++r)
                outp[(size_t)(mf * 16 + orow + r) * 512 + nf * 16 + frow] =
                    acc[mf][nf][r] + bv[nf];
}

extern "C" void kernel_launch(void* const* d_in, const int* in_sizes, int n_in,
                              void* d_out, int out_size, void* d_ws, size_t ws_size,
                              hipStream_t stream) {
    const float* X    = (const float*)d_in[0];
    const float* Wt   = (const float*)d_in[1];
    const float* Bias = (const float*)d_in[2];
    float* Out        = (float*)d_out;

    dim3 grid(2048);
    bgemm_bt_bias<<<grid, TB, 0, stream>>>(X, Wt, Bias, Out);
}